// Round 2
// baseline (217.464 us; speedup 1.0000x reference)
//
#include <hip/hip_runtime.h>

typedef __bf16 bf16x8 __attribute__((ext_vector_type(8)));
typedef __bf16 bf16x2 __attribute__((ext_vector_type(2)));
typedef float  f32x4  __attribute__((ext_vector_type(4)));
typedef float  f32x16 __attribute__((ext_vector_type(16)));
typedef unsigned short u16;
typedef unsigned u32x2 __attribute__((ext_vector_type(2)));
typedef unsigned u32x4 __attribute__((ext_vector_type(4)));

// native RNE f32->bf16 (compiler emits v_cvt_pk_bf16_f32)
__device__ __forceinline__ u16 f2bf(float f) {
  return __builtin_bit_cast(u16, (__bf16)f);
}
// pack two f32 -> dword of 2 bf16 (lo = bits 0-15)
__device__ __forceinline__ unsigned pack2(float lo, float hi) {
  bf16x2 t;
  t[0] = (__bf16)lo; t[1] = (__bf16)hi;
  return __builtin_bit_cast(unsigned, t);
}

#define GLOAD16(g, l) __builtin_amdgcn_global_load_lds( \
    (__attribute__((address_space(1))) void*)(void*)(g), \
    (__attribute__((address_space(3))) void*)(l), 16, 0, 0)

// log2(e)/8 : folds softmax scale (1/sqrt(64)) and exp->exp2 conversion into Q
#define QSCALE 0.18033688011112042f

// ---------------------------------------------------------------- converts
__global__ __launch_bounds__(256) void cvt_bf16(const float* __restrict__ src,
                                                unsigned* __restrict__ dst, int n8) {
  int i = blockIdx.x * 256 + threadIdx.x;
  if (i >= n8) return;
  const float4* s = (const float4*)src + 2 * (size_t)i;
  float4 a = s[0], b = s[1];
  u32x4 o = {pack2(a.x, a.y), pack2(a.z, a.w), pack2(b.x, b.y), pack2(b.z, b.w)};
  *((u32x4*)dst + i) = o;
}

// ---------------------------------------------------------------- GEMM (TN)
// C[m][n] = sum_k A[m][k]*B[n][k]; 128x128 tile, BK=32, double-buffered LDS,
// one barrier per K-step (stage(next) overlaps compute(cur)).
template<int EPI>
__global__ __launch_bounds__(256) void gemm_tn(
    const u16* __restrict__ A, const u16* __restrict__ B,
    const float* __restrict__ bias, float* __restrict__ outF,
    u16* __restrict__ qws, u16* __restrict__ kws, u16* __restrict__ vtws,
    int M, int N, int K) {
  __shared__ __align__(16) u16 As[8192];   // 2 x [128][32]
  __shared__ __align__(16) u16 Bs[8192];
  const int tid = threadIdx.x;
  const int ln = tid & 63, wv = tid >> 6;
  const int wr = wv >> 1, wc = wv & 1;
  const int m0 = blockIdx.x * 128, n0 = blockIdx.y * 128;

  f32x4 acc[4][4] = {};

  const int c0 = tid, c1 = tid + 256;
  const int r0 = c0 >> 2, kc0 = ((c0 & 3) ^ ((r0 >> 1) & 3)) * 8;
  const int r1 = c1 >> 2, kc1 = ((c1 & 3) ^ ((r1 >> 1) & 3)) * 8;
  const u16* ag0 = A + (size_t)(m0 + r0) * K + kc0;
  const u16* ag1 = A + (size_t)(m0 + r1) * K + kc1;
  const u16* bg0 = B + (size_t)(n0 + r0) * K + kc0;
  const u16* bg1 = B + (size_t)(n0 + r1) * K + kc1;

  // prologue: stage k0=0 into buffer 0
  GLOAD16(ag0, As + wv * 512);
  GLOAD16(ag1, As + 2048 + wv * 512);
  GLOAD16(bg0, Bs + wv * 512);
  GLOAD16(bg1, Bs + 2048 + wv * 512);
  __syncthreads();

  int cur = 0;
  for (int k0 = 0; k0 < K; k0 += 32) {
    const int nxt = cur ^ 1;
    if (k0 + 32 < K) {
      GLOAD16(ag0 + k0 + 32, As + nxt * 4096 + wv * 512);
      GLOAD16(ag1 + k0 + 32, As + nxt * 4096 + 2048 + wv * 512);
      GLOAD16(bg0 + k0 + 32, Bs + nxt * 4096 + wv * 512);
      GLOAD16(bg1 + k0 + 32, Bs + nxt * 4096 + 2048 + wv * 512);
    }
    const u16* ab = As + cur * 4096;
    const u16* bb = Bs + cur * 4096;
    bf16x8 af[4], bfr[4];
#pragma unroll
    for (int i = 0; i < 4; ++i) {
      int ra = wr * 64 + i * 16 + (ln & 15);
      af[i] = *(const bf16x8*)(ab + ra * 32 + (((ln >> 4) ^ ((ra >> 1) & 3)) * 8));
      int rb = wc * 64 + i * 16 + (ln & 15);
      bfr[i] = *(const bf16x8*)(bb + rb * 32 + (((ln >> 4) ^ ((rb >> 1) & 3)) * 8));
    }
#pragma unroll
    for (int i = 0; i < 4; ++i)
#pragma unroll
      for (int j = 0; j < 4; ++j)
        acc[i][j] = __builtin_amdgcn_mfma_f32_16x16x32_bf16(af[i], bfr[j], acc[i][j], 0, 0, 0);
    __syncthreads();
    cur = nxt;
  }

  if (EPI == 1) {
#pragma unroll
    for (int j = 0; j < 4; ++j) {
      int col = n0 + wc * 64 + j * 16 + (ln & 15);
      float bj = bias[col];
#pragma unroll
      for (int i = 0; i < 4; ++i) {
        int mr = m0 + wr * 64 + i * 16 + ((ln >> 4) << 2);
#pragma unroll
        for (int r = 0; r < 4; ++r)
          outF[(size_t)(mr + r) * N + col] = acc[i][j][r] + bj;
      }
    }
  } else {
    const int s = n0 / 768;  // 0=q 1=k 2=v (block-uniform; 768%128==0)
#pragma unroll
    for (int j = 0; j < 4; ++j) {
      int col = n0 + wc * 64 + j * 16 + (ln & 15);
      float bj = bias[col];
      int ns = col - s * 768;
      int h = ns >> 6, d = ns & 63;
#pragma unroll
      for (int i = 0; i < 4; ++i) {
        int m = m0 + wr * 64 + i * 16 + ((ln >> 4) << 2);
        int b = m >> 11, iseq = m & 2047;
        size_t bh = (size_t)(b * 12 + h);
        if (s == 0) {
#pragma unroll
          for (int r = 0; r < 4; ++r)
            qws[(bh * 2048 + iseq + r) * 64 + d] = f2bf((acc[i][j][r] + bj) * QSCALE);
        } else if (s == 1) {
#pragma unroll
          for (int r = 0; r < 4; ++r)
            kws[(bh * 2048 + iseq + r) * 64 + d] = f2bf(acc[i][j][r] + bj);
        } else {
          u32x2 pk = {pack2(acc[i][j][0] + bj, acc[i][j][1] + bj),
                      pack2(acc[i][j][2] + bj, acc[i][j][3] + bj)};
          *(u32x2*)(vtws + (bh * 64 + d) * 2048 + iseq) = pk;  // v transposed
        }
      }
    }
  }
}

// ---------------------------------------------------------------- flash attn
// R1 post-mortem: halving LDS reads (64q/wave, pair-split KV) was exactly
// offset by losing a block/CU (64KB LDS -> 2 blocks, 16% occupancy). The
// kernel is latency-bound, grid-capped at 12 waves/CU; we must keep ALL of
// them. R2: keep the 64q/wave dataflow but drop V-staging entirely — V^T
// fragments are 16B/lane, L2-resident (512KB K+V per bh, consecutive blocks
// share bh), so PV reads them straight from global (guide m169: V-staging on
// L2-fit data is pure overhead). LDS: K only, 2 pairs x dbuf x 8KB = 32KB
// (+1KB l-exchange) -> 3 blocks/CU restored. LDS reads drop another 2x
// (K-side only), staged bytes halve, GLOADs halve.
// Swapped-operand 32x32x16: S^T = mfma(K, Q^T); lane owns q=ln&31.
// No max-tracking (shift-invariant softmax, exp2 domain |s|~O(3) << 127).
// K rows staged pi-permuted (swap bits 2<->3 of global row) so every lane's
// PV B-fragment values land in its OWN registers: chunk c <- regs
// [(c&1)*8..+7] of (c<2 ? s0 : s1) — no cross-lane exchange.
// KV halves combine by plain addition of (O,l) via one LDS exchange.
#define SWZ(v) (((v) & 32) | (((v) & 31) ^ (ln & 31)))
__global__ __launch_bounds__(256, 3) void attn_fa(
    const u16* __restrict__ qws, const u16* __restrict__ kws,
    const u16* __restrict__ vtws, u16* __restrict__ aows) {
  __shared__ __align__(16) u16 Ks[16384];  // [pair][dbuf][64 k][64 d], 32KB
  __shared__ float Ls[256];                // denominator exchange
  const int tid = threadIdx.x, ln = tid & 63, wv = tid >> 6;
  const int lq = ln & 31, hi = ln >> 5;
  const int qw = wv & 1;        // which 64-q chunk of the block's 128 q
  const int p  = wv >> 1;       // which KV half
  const int bh = blockIdx.y;
  const int q0 = blockIdx.x * 128 + qw * 64;
  const int kv0 = p * 1024;
  const size_t kbase = (size_t)bh * 2048 * 64;  // [bh][n][64]
  const size_t vbase = (size_t)bh * 64 * 2048;  // [bh][64][n]

  // Q^T B-fragments, two q-groups (col=q=lq, k-rows = dc*16 + hi*8 + 0..7)
  bf16x8 qf[2][4];
#pragma unroll
  for (int g = 0; g < 2; ++g) {
    const u16* qp = qws + kbase + (size_t)(q0 + g * 32 + lq) * 64 + hi * 8;
#pragma unroll
    for (int dc = 0; dc < 4; ++dc) qf[g][dc] = *(const bf16x8*)(qp + dc * 16);
  }

  const f32x16 zc = {};
  f32x16 o0[2] = {}, o1[2] = {};           // O^T per q-group: d 0..31 / 32..63
  float ls0[2] = {0.f, 0.f}, ls1[2] = {0.f, 0.f};  // denom partial sums

  // hoisted K LDS read offsets (loop-invariant)
  int offL[4], offH[4];
#pragma unroll
  for (int dc = 0; dc < 4; ++dc) {
    const int ch = dc * 2 + hi;
    offL[dc] = lq * 64 + ((ch ^ (lq & 7)) * 8);
    offH[dc] = (32 + lq) * 64 + ((ch ^ (lq & 7)) * 8);
  }

  // V^T direct-from-global row pointers (per-lane): rows d=lq / 32+lq
  const u16* vrow0 = vtws + vbase + (size_t)lq * 2048 + kv0;
  const u16* vrow1 = vrow0 + (size_t)32 * 2048;

  // K staging: per pair, 128 threads stage 8KB per tile, 4 GLOAD16 each.
  // slot s = lt + j*128 -> row (lt>>3)+16j, chunk lt&7; LDS linear by slot.
  const int lt = tid & 127;
  const int r0 = lt >> 3;
  const int pr0 = (r0 & ~12) | ((r0 & 4) << 1) | ((r0 & 8) >> 1);  // pi: swap bits 2,3
  const int sc = ((lt & 7) ^ (r0 & 7)) * 8;  // swizzled source chunk
  const u16* kg = kws + kbase + (size_t)(kv0 + pr0) * 64 + sc;
  u16* ksb = Ks + p * 8192;
  const int sd = qw * 512;   // wave's slot base within a buffer

  // prologue: stage K tile kb=0 into buffer 0
#pragma unroll
  for (int j = 0; j < 4; ++j) GLOAD16(kg + j * 1024, ksb + sd + j * 1024);
  __syncthreads();

  int cur = 0;
  for (int kb = 0; kb < 1024; kb += 64) {
    const int nxt = cur ^ 1;
    if (kb + 64 < 1024) {
#pragma unroll
      for (int j = 0; j < 4; ++j)
        GLOAD16(kg + (size_t)(kb + 64) * 64 + j * 1024, ksb + nxt * 4096 + sd + j * 1024);
    }
    const u16* kbuf = ksb + cur * 4096;

    // S^T[k][q]: A = K-tile rows (shared LDS load), B = Q^T per group
    f32x16 s0[2], s1[2];
    {
      bf16x8 ka = *(const bf16x8*)(kbuf + offL[0]);
      bf16x8 kh = *(const bf16x8*)(kbuf + offH[0]);
      s0[0] = __builtin_amdgcn_mfma_f32_32x32x16_bf16(ka, qf[0][0], zc, 0, 0, 0);
      s0[1] = __builtin_amdgcn_mfma_f32_32x32x16_bf16(ka, qf[1][0], zc, 0, 0, 0);
      s1[0] = __builtin_amdgcn_mfma_f32_32x32x16_bf16(kh, qf[0][0], zc, 0, 0, 0);
      s1[1] = __builtin_amdgcn_mfma_f32_32x32x16_bf16(kh, qf[1][0], zc, 0, 0, 0);
    }
#pragma unroll
    for (int dc = 1; dc < 4; ++dc) {
      bf16x8 ka = *(const bf16x8*)(kbuf + offL[dc]);
      bf16x8 kh = *(const bf16x8*)(kbuf + offH[dc]);
      s0[0] = __builtin_amdgcn_mfma_f32_32x32x16_bf16(ka, qf[0][dc], s0[0], 0, 0, 0);
      s0[1] = __builtin_amdgcn_mfma_f32_32x32x16_bf16(ka, qf[1][dc], s0[1], 0, 0, 0);
      s1[0] = __builtin_amdgcn_mfma_f32_32x32x16_bf16(kh, qf[0][dc], s1[0], 0, 0, 0);
      s1[1] = __builtin_amdgcn_mfma_f32_32x32x16_bf16(kh, qf[1][dc], s1[1], 0, 0, 0);
    }

    // P = exp2(S) (shift-invariant softmax); denominator summed on VALU
#pragma unroll
    for (int g = 0; g < 2; ++g) {
      float a0 = 0.f, a1 = 0.f;
#pragma unroll
      for (int r = 0; r < 16; ++r) {
        float e = __builtin_amdgcn_exp2f(s0[g][r]); s0[g][r] = e; a0 += e;
      }
#pragma unroll
      for (int r = 0; r < 16; ++r) {
        float e = __builtin_amdgcn_exp2f(s1[g][r]); s1[g][r] = e; a1 += e;
      }
      ls0[g] += a0; ls1[g] += a1;
    }

    // PV: V fragments straight from global (L2-resident), feed both q-groups.
    // With pi-permuted K rows, chunk c (k = c*16 + hi*8 + {0..7}) is regs
    // [(c&1)*8..+7] of (c<2 ? s0 : s1) for BOTH hi halves — in-lane pack.
    const u16* vp0 = vrow0 + kb;
    const u16* vp1 = vrow1 + kb;
#pragma unroll
    for (int c = 0; c < 4; ++c) {
      bf16x8 va = *(const bf16x8*)(vp0 + (c * 2 + hi) * 8);
      bf16x8 vb = *(const bf16x8*)(vp1 + (c * 2 + hi) * 8);
#pragma unroll
      for (int g = 0; g < 2; ++g) {
        const f32x16& src = (c < 2) ? s0[g] : s1[g];
        const int base = (c & 1) * 8;
        u32x4 pw = {pack2(src[base + 0], src[base + 1]),
                    pack2(src[base + 2], src[base + 3]),
                    pack2(src[base + 4], src[base + 5]),
                    pack2(src[base + 6], src[base + 7])};
        bf16x8 pfrag = __builtin_bit_cast(bf16x8, pw);
        o0[g] = __builtin_amdgcn_mfma_f32_32x32x16_bf16(va, pfrag, o0[g], 0, 0, 0);
        o1[g] = __builtin_amdgcn_mfma_f32_32x32x16_bf16(vb, pfrag, o1[g], 0, 0, 0);
      }
    }
    __syncthreads();
    cur = nxt;
  }

  // per-wave denominator: lane holds 32 of 64 k-rows; partner lane ln^32 has
  // the rest (same q = lq). After shfl both lanes hold the half-KV total.
  float lg[2];
#pragma unroll
  for (int g = 0; g < 2; ++g) {
    lg[g] = ls0[g] + ls1[g];
    lg[g] += __shfl_xor(lg[g], 32);
  }

  // combine KV halves: waves p=1 export (O,l); waves p=0 add + store.
  // O exchange packed into Ks (32KB = 2 qw-groups x 64 lanes x 64 f32) with
  // XOR swizzle: value v -> col (v&32)|((v&31)^(ln&31)) — conflict-free
  // (lanes ln, ln^32 alias 2-way = free). l goes via Ls.
  float* exO = (float*)Ks + qw * 4096 + ln * 64;
  if (p == 1) {
#pragma unroll
    for (int r = 0; r < 16; ++r) {
      exO[SWZ(r)]      = o0[0][r];
      exO[SWZ(16 + r)] = o1[0][r];
      exO[SWZ(32 + r)] = o0[1][r];
      exO[SWZ(48 + r)] = o1[1][r];
    }
    Ls[qw * 128 + ln * 2 + 0] = lg[0];
    Ls[qw * 128 + ln * 2 + 1] = lg[1];
  }
  __syncthreads();
  if (p == 0) {
#pragma unroll
    for (int r = 0; r < 16; ++r) {
      o0[0][r] += exO[SWZ(r)];
      o1[0][r] += exO[SWZ(16 + r)];
      o0[1][r] += exO[SWZ(32 + r)];
      o1[1][r] += exO[SWZ(48 + r)];
    }
    lg[0] += Ls[qw * 128 + ln * 2 + 0];
    lg[1] += Ls[qw * 128 + ln * 2 + 1];

    const int b = bh / 12, h = bh % 12;
#pragma unroll
    for (int g = 0; g < 2; ++g) {
      const float rl = 1.0f / lg[g];
      u16* orow = aows + (size_t)(b * 2048 + q0 + g * 32 + lq) * 768 + h * 64;
#pragma unroll
      for (int t = 0; t < 4; ++t) {
        u32x2 pk0 = {pack2(o0[g][4 * t + 0] * rl, o0[g][4 * t + 1] * rl),
                     pack2(o0[g][4 * t + 2] * rl, o0[g][4 * t + 3] * rl)};
        u32x2 pk1 = {pack2(o1[g][4 * t + 0] * rl, o1[g][4 * t + 1] * rl),
                     pack2(o1[g][4 * t + 2] * rl, o1[g][4 * t + 3] * rl)};
        *(u32x2*)(orow + t * 8 + 4 * hi)      = pk0;   // d = 8t+4hi+r
        *(u32x2*)(orow + 32 + t * 8 + 4 * hi) = pk1;   // d = 32+8t+4hi+r
      }
    }
  }
}

// ---------------------------------------------------------------- launch
extern "C" void kernel_launch(void* const* d_in, const int* in_sizes, int n_in,
                              void* d_out, int out_size, void* d_ws, size_t ws_size,
                              hipStream_t stream) {
  const float* x     = (const float*)d_in[0];
  const float* Wqkv  = (const float*)d_in[1];
  const float* bqkv  = (const float*)d_in[2];
  const float* Wproj = (const float*)d_in[3];
  const float* bproj = (const float*)d_in[4];
  float* out = (float*)d_out;

  u16* xb   = (u16*)d_ws;          // 6291456
  u16* wqb  = xb  + 6291456;       // 1769472
  u16* wpb  = wqb + 1769472;       // 589824
  u16* qws  = wpb + 589824;        // 6291456  [bh][n][64], pre-scaled QSCALE
  u16* kws  = qws + 6291456;       // 6291456  [bh][n][64]
  u16* vtws = kws + 6291456;       // 6291456  [bh][64][n]
  u16* aows = vtws + 6291456;      // 6291456  [b*2048+q][768]

  cvt_bf16<<<6291456 / 8 / 256, 256, 0, stream>>>(x, (unsigned*)xb, 6291456 / 8);
  cvt_bf16<<<1769472 / 8 / 256, 256, 0, stream>>>(Wqkv, (unsigned*)wqb, 1769472 / 8);
  cvt_bf16<<<589824 / 8 / 256, 256, 0, stream>>>(Wproj, (unsigned*)wpb, 589824 / 8);

  gemm_tn<0><<<dim3(64, 18), 256, 0, stream>>>(xb, wqb, bqkv, nullptr,
                                               qws, kws, vtws, 8192, 2304, 768);
  attn_fa<<<dim3(16, 48), 256, 0, stream>>>(qws, kws, vtws, aows);
  gemm_tn<1><<<dim3(64, 6), 256, 0, stream>>>(aows, wpb, bproj, out,
                                              nullptr, nullptr, nullptr,
                                              8192, 768, 768);
}

// Round 3
// 214.717 us; speedup vs baseline: 1.0128x; 1.0128x over previous
//
#include <hip/hip_runtime.h>

typedef __bf16 bf16x8 __attribute__((ext_vector_type(8)));
typedef __bf16 bf16x2 __attribute__((ext_vector_type(2)));
typedef float  f32x4  __attribute__((ext_vector_type(4)));
typedef float  f32x16 __attribute__((ext_vector_type(16)));
typedef unsigned short u16;
typedef unsigned u32x2 __attribute__((ext_vector_type(2)));
typedef unsigned u32x4 __attribute__((ext_vector_type(4)));

// native RNE f32->bf16 (compiler emits v_cvt_pk_bf16_f32)
__device__ __forceinline__ u16 f2bf(float f) {
  return __builtin_bit_cast(u16, (__bf16)f);
}
// pack two f32 -> dword of 2 bf16 (lo = bits 0-15)
__device__ __forceinline__ unsigned pack2(float lo, float hi) {
  bf16x2 t;
  t[0] = (__bf16)lo; t[1] = (__bf16)hi;
  return __builtin_bit_cast(unsigned, t);
}

#define GLOAD16(g, l) __builtin_amdgcn_global_load_lds( \
    (__attribute__((address_space(1))) void*)(void*)(g), \
    (__attribute__((address_space(3))) void*)(l), 16, 0, 0)

// log2(e)/8 : folds softmax scale (1/sqrt(64)) and exp->exp2 conversion into Q
#define QSCALE 0.18033688011112042f

// ---------------------------------------------------------------- converts
__global__ __launch_bounds__(256) void cvt_bf16(const float* __restrict__ src,
                                                unsigned* __restrict__ dst, int n8) {
  int i = blockIdx.x * 256 + threadIdx.x;
  if (i >= n8) return;
  const float4* s = (const float4*)src + 2 * (size_t)i;
  float4 a = s[0], b = s[1];
  u32x4 o = {pack2(a.x, a.y), pack2(a.z, a.w), pack2(b.x, b.y), pack2(b.z, b.w)};
  *((u32x4*)dst + i) = o;
}

// ---------------------------------------------------------------- GEMM (TN)
// C[m][n] = sum_k A[m][k]*B[n][k]; 128x128 tile, BK=32, double-buffered LDS,
// one barrier per K-step (stage(next) overlaps compute(cur)).
template<int EPI>
__global__ __launch_bounds__(256) void gemm_tn(
    const u16* __restrict__ A, const u16* __restrict__ B,
    const float* __restrict__ bias, float* __restrict__ outF,
    u16* __restrict__ qws, u16* __restrict__ kws, u16* __restrict__ vtws,
    int M, int N, int K) {
  __shared__ __align__(16) u16 As[8192];   // 2 x [128][32]
  __shared__ __align__(16) u16 Bs[8192];
  const int tid = threadIdx.x;
  const int ln = tid & 63, wv = tid >> 6;
  const int wr = wv >> 1, wc = wv & 1;
  const int m0 = blockIdx.x * 128, n0 = blockIdx.y * 128;

  f32x4 acc[4][4] = {};

  const int c0 = tid, c1 = tid + 256;
  const int r0 = c0 >> 2, kc0 = ((c0 & 3) ^ ((r0 >> 1) & 3)) * 8;
  const int r1 = c1 >> 2, kc1 = ((c1 & 3) ^ ((r1 >> 1) & 3)) * 8;
  const u16* ag0 = A + (size_t)(m0 + r0) * K + kc0;
  const u16* ag1 = A + (size_t)(m0 + r1) * K + kc1;
  const u16* bg0 = B + (size_t)(n0 + r0) * K + kc0;
  const u16* bg1 = B + (size_t)(n0 + r1) * K + kc1;

  // prologue: stage k0=0 into buffer 0
  GLOAD16(ag0, As + wv * 512);
  GLOAD16(ag1, As + 2048 + wv * 512);
  GLOAD16(bg0, Bs + wv * 512);
  GLOAD16(bg1, Bs + 2048 + wv * 512);
  __syncthreads();

  int cur = 0;
  for (int k0 = 0; k0 < K; k0 += 32) {
    const int nxt = cur ^ 1;
    if (k0 + 32 < K) {
      GLOAD16(ag0 + k0 + 32, As + nxt * 4096 + wv * 512);
      GLOAD16(ag1 + k0 + 32, As + nxt * 4096 + 2048 + wv * 512);
      GLOAD16(bg0 + k0 + 32, Bs + nxt * 4096 + wv * 512);
      GLOAD16(bg1 + k0 + 32, Bs + nxt * 4096 + 2048 + wv * 512);
    }
    const u16* ab = As + cur * 4096;
    const u16* bb = Bs + cur * 4096;
    bf16x8 af[4], bfr[4];
#pragma unroll
    for (int i = 0; i < 4; ++i) {
      int ra = wr * 64 + i * 16 + (ln & 15);
      af[i] = *(const bf16x8*)(ab + ra * 32 + (((ln >> 4) ^ ((ra >> 1) & 3)) * 8));
      int rb = wc * 64 + i * 16 + (ln & 15);
      bfr[i] = *(const bf16x8*)(bb + rb * 32 + (((ln >> 4) ^ ((rb >> 1) & 3)) * 8));
    }
#pragma unroll
    for (int i = 0; i < 4; ++i)
#pragma unroll
      for (int j = 0; j < 4; ++j)
        acc[i][j] = __builtin_amdgcn_mfma_f32_16x16x32_bf16(af[i], bfr[j], acc[i][j], 0, 0, 0);
    __syncthreads();
    cur = nxt;
  }

  if (EPI == 1) {
#pragma unroll
    for (int j = 0; j < 4; ++j) {
      int col = n0 + wc * 64 + j * 16 + (ln & 15);
      float bj = bias[col];
#pragma unroll
      for (int i = 0; i < 4; ++i) {
        int mr = m0 + wr * 64 + i * 16 + ((ln >> 4) << 2);
#pragma unroll
        for (int r = 0; r < 4; ++r)
          outF[(size_t)(mr + r) * N + col] = acc[i][j][r] + bj;
      }
    }
  } else {
    const int s = n0 / 768;  // 0=q 1=k 2=v (block-uniform; 768%128==0)
#pragma unroll
    for (int j = 0; j < 4; ++j) {
      int col = n0 + wc * 64 + j * 16 + (ln & 15);
      float bj = bias[col];
      int ns = col - s * 768;
      int h = ns >> 6, d = ns & 63;
#pragma unroll
      for (int i = 0; i < 4; ++i) {
        int m = m0 + wr * 64 + i * 16 + ((ln >> 4) << 2);
        int b = m >> 11, iseq = m & 2047;
        size_t bh = (size_t)(b * 12 + h);
        if (s == 0) {
#pragma unroll
          for (int r = 0; r < 4; ++r)
            qws[(bh * 2048 + iseq + r) * 64 + d] = f2bf((acc[i][j][r] + bj) * QSCALE);
        } else if (s == 1) {
#pragma unroll
          for (int r = 0; r < 4; ++r)
            kws[(bh * 2048 + iseq + r) * 64 + d] = f2bf(acc[i][j][r] + bj);
        } else {
          // V transposed, TILE-BLOCKED: [bh][tile=iseq>>6][d][k=iseq&63].
          // 64x64 tile = contiguous 8KB -> attn's PV reads are line-dense.
          u32x2 pk = {pack2(acc[i][j][0] + bj, acc[i][j][1] + bj),
                      pack2(acc[i][j][2] + bj, acc[i][j][3] + bj)};
          *(u32x2*)(vtws + ((bh * 32 + (iseq >> 6)) * 64 + d) * 64 + (iseq & 63)) = pk;
        }
      }
    }
  }
}

// ---------------------------------------------------------------- flash attn
// R2 post-mortem: direct V reads from [bh][64][2048] were 16B/lane at 4KB
// stride -> 64 cache lines per wave-load, L2 thrash (FETCH 350MB, WRITE
// amplification 96MB). Fix: V^T stored tile-blocked [bh][32][64 d][64 k]
// (contiguous 8KB per KV-tile) so the 8 PV wave-loads per tile cover the
// tile line-densely and it stays L1-resident across them. K unchanged
// ([bh][n][64] is already tile-contiguous, staged to LDS pi-permuted).
// Also: bijective XCD-chunked block swizzle — each XCD owns 6 bh, so the
// per-XCD K+V working set is 3MB < 4MB L2 (was: all 48 bh per XCD).
// Structure (from R1/R2): 4 waves; wave = (qw, p) handles 64 q x 1024 KV.
// Swapped-operand 32x32x16: S^T = mfma(K, Q^T); lane owns q=ln&31; exp2
// shift-invariant softmax (no max tracking); denominator on VALU; KV halves
// combine by plain (O,l) addition via one LDS exchange at the epilogue.
#define SWZ(v) (((v) & 32) | (((v) & 31) ^ (ln & 31)))
__global__ __launch_bounds__(256, 3) void attn_fa(
    const u16* __restrict__ qws, const u16* __restrict__ kws,
    const u16* __restrict__ vtws, u16* __restrict__ aows) {
  __shared__ __align__(16) u16 Ks[16384];  // [pair][dbuf][64 k][64 d], 32KB
  __shared__ float Ls[256];                // denominator exchange
  const int tid = threadIdx.x, ln = tid & 63, wv = tid >> 6;
  const int lq = ln & 31, hi = ln >> 5;
  const int qw = wv & 1;        // which 64-q chunk of the block's 128 q
  const int p  = wv >> 1;       // which KV half

  // XCD-chunked swizzle: flat = y*16+x; xcd = flat&7 owns bh in [6*xcd,6*xcd+6)
  const int flat = blockIdx.y * 16 + blockIdx.x;
  const int xcd = flat & 7, jj = flat >> 3;
  const int bh = xcd * 6 + (jj % 6);
  const int q0 = (jj / 6) * 128 + qw * 64;

  const int kv0 = p * 1024;
  const size_t kbase = (size_t)bh * 2048 * 64;   // [bh][n][64]
  const size_t vbase = (size_t)bh * 32 * 4096;   // [bh][tile][64 d][64 k]

  // Q^T B-fragments, two q-groups (col=q=lq, k-rows = dc*16 + hi*8 + 0..7)
  bf16x8 qf[2][4];
#pragma unroll
  for (int g = 0; g < 2; ++g) {
    const u16* qp = qws + kbase + (size_t)(q0 + g * 32 + lq) * 64 + hi * 8;
#pragma unroll
    for (int dc = 0; dc < 4; ++dc) qf[g][dc] = *(const bf16x8*)(qp + dc * 16);
  }

  const f32x16 zc = {};
  f32x16 o0[2] = {}, o1[2] = {};           // O^T per q-group: d 0..31 / 32..63
  float ls0[2] = {0.f, 0.f}, ls1[2] = {0.f, 0.f};  // denom partial sums

  // hoisted K LDS read offsets (loop-invariant)
  int offL[4], offH[4];
#pragma unroll
  for (int dc = 0; dc < 4; ++dc) {
    const int ch = dc * 2 + hi;
    offL[dc] = lq * 64 + ((ch ^ (lq & 7)) * 8);
    offH[dc] = (32 + lq) * 64 + ((ch ^ (lq & 7)) * 8);
  }

  // V^T tiled direct-read bases: rows d=lq / 32+lq, chunk parity hi
  const u16* vl0 = vtws + vbase + (size_t)(kv0 >> 6) * 4096 + lq * 64 + hi * 8;
  const u16* vl1 = vl0 + 32 * 64;

  // K staging: per pair, 128 threads stage 8KB per tile, 4 GLOAD16 each.
  // slot s = lt + j*128 -> row (lt>>3)+16j, chunk lt&7; LDS linear by slot.
  const int lt = tid & 127;
  const int r0 = lt >> 3;
  const int pr0 = (r0 & ~12) | ((r0 & 4) << 1) | ((r0 & 8) >> 1);  // pi: swap bits 2,3
  const int sc = ((lt & 7) ^ (r0 & 7)) * 8;  // swizzled source chunk
  const u16* kg = kws + kbase + (size_t)(kv0 + pr0) * 64 + sc;
  u16* ksb = Ks + p * 8192;
  const int sd = qw * 512;   // wave's slot base within a buffer

  // prologue: stage K tile kb=0 into buffer 0
#pragma unroll
  for (int j = 0; j < 4; ++j) GLOAD16(kg + j * 1024, ksb + sd + j * 1024);
  __syncthreads();

  int cur = 0;
  for (int kb = 0; kb < 1024; kb += 64) {
    const int nxt = cur ^ 1;
    if (kb + 64 < 1024) {
#pragma unroll
      for (int j = 0; j < 4; ++j)
        GLOAD16(kg + (size_t)(kb + 64) * 64 + j * 1024, ksb + nxt * 4096 + sd + j * 1024);
    }
    const u16* kbuf = ksb + cur * 4096;

    // S^T[k][q]: A = K-tile rows (shared LDS load), B = Q^T per group
    f32x16 s0[2], s1[2];
    {
      bf16x8 ka = *(const bf16x8*)(kbuf + offL[0]);
      bf16x8 kh = *(const bf16x8*)(kbuf + offH[0]);
      s0[0] = __builtin_amdgcn_mfma_f32_32x32x16_bf16(ka, qf[0][0], zc, 0, 0, 0);
      s0[1] = __builtin_amdgcn_mfma_f32_32x32x16_bf16(ka, qf[1][0], zc, 0, 0, 0);
      s1[0] = __builtin_amdgcn_mfma_f32_32x32x16_bf16(kh, qf[0][0], zc, 0, 0, 0);
      s1[1] = __builtin_amdgcn_mfma_f32_32x32x16_bf16(kh, qf[1][0], zc, 0, 0, 0);
    }
#pragma unroll
    for (int dc = 1; dc < 4; ++dc) {
      bf16x8 ka = *(const bf16x8*)(kbuf + offL[dc]);
      bf16x8 kh = *(const bf16x8*)(kbuf + offH[dc]);
      s0[0] = __builtin_amdgcn_mfma_f32_32x32x16_bf16(ka, qf[0][dc], s0[0], 0, 0, 0);
      s0[1] = __builtin_amdgcn_mfma_f32_32x32x16_bf16(ka, qf[1][dc], s0[1], 0, 0, 0);
      s1[0] = __builtin_amdgcn_mfma_f32_32x32x16_bf16(kh, qf[0][dc], s1[0], 0, 0, 0);
      s1[1] = __builtin_amdgcn_mfma_f32_32x32x16_bf16(kh, qf[1][dc], s1[1], 0, 0, 0);
    }

    // V tile loads (direct global, L1/L2-resident tile) issued BEFORE exp2
    // so the trans-op latency covers the VMEM latency.
    const u16* vt0 = vl0 + (kb >> 6) * 4096;
    const u16* vt1 = vl1 + (kb >> 6) * 4096;
    bf16x8 vfa[4], vfb[4];
#pragma unroll
    for (int c = 0; c < 4; ++c) {
      vfa[c] = *(const bf16x8*)(vt0 + c * 16);
      vfb[c] = *(const bf16x8*)(vt1 + c * 16);
    }

    // P = exp2(S) (shift-invariant softmax); denominator summed on VALU
#pragma unroll
    for (int g = 0; g < 2; ++g) {
      float a0 = 0.f, a1 = 0.f;
#pragma unroll
      for (int r = 0; r < 16; ++r) {
        float e = __builtin_amdgcn_exp2f(s0[g][r]); s0[g][r] = e; a0 += e;
      }
#pragma unroll
      for (int r = 0; r < 16; ++r) {
        float e = __builtin_amdgcn_exp2f(s1[g][r]); s1[g][r] = e; a1 += e;
      }
      ls0[g] += a0; ls1[g] += a1;
    }

    // PV: V fragments feed both q-groups. With pi-permuted K rows, chunk c
    // (k = c*16 + hi*8 + {0..7}) is regs [(c&1)*8..+7] of (c<2 ? s0 : s1)
    // for BOTH hi halves — pure in-lane pack, no cross-lane exchange.
#pragma unroll
    for (int c = 0; c < 4; ++c) {
#pragma unroll
      for (int g = 0; g < 2; ++g) {
        const f32x16& src = (c < 2) ? s0[g] : s1[g];
        const int base = (c & 1) * 8;
        u32x4 pw = {pack2(src[base + 0], src[base + 1]),
                    pack2(src[base + 2], src[base + 3]),
                    pack2(src[base + 4], src[base + 5]),
                    pack2(src[base + 6], src[base + 7])};
        bf16x8 pfrag = __builtin_bit_cast(bf16x8, pw);
        o0[g] = __builtin_amdgcn_mfma_f32_32x32x16_bf16(vfa[c], pfrag, o0[g], 0, 0, 0);
        o1[g] = __builtin_amdgcn_mfma_f32_32x32x16_bf16(vfb[c], pfrag, o1[g], 0, 0, 0);
      }
    }
    __syncthreads();
    cur = nxt;
  }

  // per-wave denominator: lane holds 32 of 64 k-rows; partner lane ln^32 has
  // the rest (same q = lq). After shfl both lanes hold the half-KV total.
  float lg[2];
#pragma unroll
  for (int g = 0; g < 2; ++g) {
    lg[g] = ls0[g] + ls1[g];
    lg[g] += __shfl_xor(lg[g], 32);
  }

  // combine KV halves: waves p=1 export (O,l); waves p=0 add + store.
  // O exchange packed into Ks (32KB = 2 qw-groups x 64 lanes x 64 f32) with
  // XOR swizzle: value v -> col (v&32)|((v&31)^(ln&31)) — conflict-free
  // (lanes ln, ln^32 alias 2-way = free). l goes via Ls.
  float* exO = (float*)Ks + qw * 4096 + ln * 64;
  if (p == 1) {
#pragma unroll
    for (int r = 0; r < 16; ++r) {
      exO[SWZ(r)]      = o0[0][r];
      exO[SWZ(16 + r)] = o1[0][r];
      exO[SWZ(32 + r)] = o0[1][r];
      exO[SWZ(48 + r)] = o1[1][r];
    }
    Ls[qw * 128 + ln * 2 + 0] = lg[0];
    Ls[qw * 128 + ln * 2 + 1] = lg[1];
  }
  __syncthreads();
  if (p == 0) {
#pragma unroll
    for (int r = 0; r < 16; ++r) {
      o0[0][r] += exO[SWZ(r)];
      o1[0][r] += exO[SWZ(16 + r)];
      o0[1][r] += exO[SWZ(32 + r)];
      o1[1][r] += exO[SWZ(48 + r)];
    }
    lg[0] += Ls[qw * 128 + ln * 2 + 0];
    lg[1] += Ls[qw * 128 + ln * 2 + 1];

    const int b = bh / 12, h = bh % 12;
#pragma unroll
    for (int g = 0; g < 2; ++g) {
      const float rl = 1.0f / lg[g];
      u16* orow = aows + (size_t)(b * 2048 + q0 + g * 32 + lq) * 768 + h * 64;
#pragma unroll
      for (int t = 0; t < 4; ++t) {
        u32x2 pk0 = {pack2(o0[g][4 * t + 0] * rl, o0[g][4 * t + 1] * rl),
                     pack2(o0[g][4 * t + 2] * rl, o0[g][4 * t + 3] * rl)};
        u32x2 pk1 = {pack2(o1[g][4 * t + 0] * rl, o1[g][4 * t + 1] * rl),
                     pack2(o1[g][4 * t + 2] * rl, o1[g][4 * t + 3] * rl)};
        *(u32x2*)(orow + t * 8 + 4 * hi)      = pk0;   // d = 8t+4hi+r
        *(u32x2*)(orow + 32 + t * 8 + 4 * hi) = pk1;   // d = 32+8t+4hi+r
      }
    }
  }
}

// ---------------------------------------------------------------- launch
extern "C" void kernel_launch(void* const* d_in, const int* in_sizes, int n_in,
                              void* d_out, int out_size, void* d_ws, size_t ws_size,
                              hipStream_t stream) {
  const float* x     = (const float*)d_in[0];
  const float* Wqkv  = (const float*)d_in[1];
  const float* bqkv  = (const float*)d_in[2];
  const float* Wproj = (const float*)d_in[3];
  const float* bproj = (const float*)d_in[4];
  float* out = (float*)d_out;

  u16* xb   = (u16*)d_ws;          // 6291456
  u16* wqb  = xb  + 6291456;       // 1769472
  u16* wpb  = wqb + 1769472;       // 589824
  u16* qws  = wpb + 589824;        // 6291456  [bh][n][64], pre-scaled QSCALE
  u16* kws  = qws + 6291456;       // 6291456  [bh][n][64]
  u16* vtws = kws + 6291456;       // 6291456  [bh][32][64][64] tile-blocked V^T
  u16* aows = vtws + 6291456;      // 6291456  [b*2048+q][768]

  cvt_bf16<<<6291456 / 8 / 256, 256, 0, stream>>>(x, (unsigned*)xb, 6291456 / 8);
  cvt_bf16<<<1769472 / 8 / 256, 256, 0, stream>>>(Wqkv, (unsigned*)wqb, 1769472 / 8);
  cvt_bf16<<<589824 / 8 / 256, 256, 0, stream>>>(Wproj, (unsigned*)wpb, 589824 / 8);

  gemm_tn<0><<<dim3(64, 18), 256, 0, stream>>>(xb, wqb, bqkv, nullptr,
                                               qws, kws, vtws, 8192, 2304, 768);
  attn_fa<<<dim3(16, 48), 256, 0, stream>>>(qws, kws, vtws, aows);
  gemm_tn<1><<<dim3(64, 6), 256, 0, stream>>>(aows, wpb, bproj, out,
                                              nullptr, nullptr, nullptr,
                                              8192, 768, 768);
}

// Round 4
// 139.129 us; speedup vs baseline: 1.5630x; 1.5433x over previous
//
#include <hip/hip_runtime.h>

typedef __bf16 bf16x8 __attribute__((ext_vector_type(8)));
typedef __bf16 bf16x2 __attribute__((ext_vector_type(2)));
typedef float  f32x4  __attribute__((ext_vector_type(4)));
typedef float  f32x16 __attribute__((ext_vector_type(16)));
typedef unsigned short u16;
typedef unsigned u32x2 __attribute__((ext_vector_type(2)));
typedef unsigned u32x4 __attribute__((ext_vector_type(4)));

// native RNE f32->bf16 (compiler emits v_cvt_pk_bf16_f32)
__device__ __forceinline__ u16 f2bf(float f) {
  return __builtin_bit_cast(u16, (__bf16)f);
}
// pack two f32 -> dword of 2 bf16 (lo = bits 0-15)
__device__ __forceinline__ unsigned pack2(float lo, float hi) {
  bf16x2 t;
  t[0] = (__bf16)lo; t[1] = (__bf16)hi;
  return __builtin_bit_cast(unsigned, t);
}

#define GLOAD16(g, l) __builtin_amdgcn_global_load_lds( \
    (__attribute__((address_space(1))) void*)(void*)(g), \
    (__attribute__((address_space(3))) void*)(l), 16, 0, 0)

// log2(e)/8 : folds softmax scale (1/sqrt(64)) and exp->exp2 conversion into Q
#define QSCALE 0.18033688011112042f

// ---------------------------------------------------------------- converts
__global__ __launch_bounds__(256) void cvt_bf16(const float* __restrict__ src,
                                                unsigned* __restrict__ dst, int n8) {
  int i = blockIdx.x * 256 + threadIdx.x;
  if (i >= n8) return;
  const float4* s = (const float4*)src + 2 * (size_t)i;
  float4 a = s[0], b = s[1];
  u32x4 o = {pack2(a.x, a.y), pack2(a.z, a.w), pack2(b.x, b.y), pack2(b.z, b.w)};
  *((u32x4*)dst + i) = o;
}

// ---------------------------------------------------------------- GEMM (TN)
// C[m][n] = sum_k A[m][k]*B[n][k]; 128x128 tile, BK=32, double-buffered LDS,
// one barrier per K-step (stage(next) overlaps compute(cur)).
template<int EPI>
__global__ __launch_bounds__(256) void gemm_tn(
    const u16* __restrict__ A, const u16* __restrict__ B,
    const float* __restrict__ bias, float* __restrict__ outF,
    u16* __restrict__ qws, u16* __restrict__ kws, u16* __restrict__ vtws,
    int M, int N, int K) {
  __shared__ __align__(16) u16 As[8192];   // 2 x [128][32]
  __shared__ __align__(16) u16 Bs[8192];
  const int tid = threadIdx.x;
  const int ln = tid & 63, wv = tid >> 6;
  const int wr = wv >> 1, wc = wv & 1;
  const int m0 = blockIdx.x * 128, n0 = blockIdx.y * 128;

  f32x4 acc[4][4] = {};

  const int c0 = tid, c1 = tid + 256;
  const int r0 = c0 >> 2, kc0 = ((c0 & 3) ^ ((r0 >> 1) & 3)) * 8;
  const int r1 = c1 >> 2, kc1 = ((c1 & 3) ^ ((r1 >> 1) & 3)) * 8;
  const u16* ag0 = A + (size_t)(m0 + r0) * K + kc0;
  const u16* ag1 = A + (size_t)(m0 + r1) * K + kc1;
  const u16* bg0 = B + (size_t)(n0 + r0) * K + kc0;
  const u16* bg1 = B + (size_t)(n0 + r1) * K + kc1;

  // prologue: stage k0=0 into buffer 0
  GLOAD16(ag0, As + wv * 512);
  GLOAD16(ag1, As + 2048 + wv * 512);
  GLOAD16(bg0, Bs + wv * 512);
  GLOAD16(bg1, Bs + 2048 + wv * 512);
  __syncthreads();

  int cur = 0;
  for (int k0 = 0; k0 < K; k0 += 32) {
    const int nxt = cur ^ 1;
    if (k0 + 32 < K) {
      GLOAD16(ag0 + k0 + 32, As + nxt * 4096 + wv * 512);
      GLOAD16(ag1 + k0 + 32, As + nxt * 4096 + 2048 + wv * 512);
      GLOAD16(bg0 + k0 + 32, Bs + nxt * 4096 + wv * 512);
      GLOAD16(bg1 + k0 + 32, Bs + nxt * 4096 + 2048 + wv * 512);
    }
    const u16* ab = As + cur * 4096;
    const u16* bb = Bs + cur * 4096;
    bf16x8 af[4], bfr[4];
#pragma unroll
    for (int i = 0; i < 4; ++i) {
      int ra = wr * 64 + i * 16 + (ln & 15);
      af[i] = *(const bf16x8*)(ab + ra * 32 + (((ln >> 4) ^ ((ra >> 1) & 3)) * 8));
      int rb = wc * 64 + i * 16 + (ln & 15);
      bfr[i] = *(const bf16x8*)(bb + rb * 32 + (((ln >> 4) ^ ((rb >> 1) & 3)) * 8));
    }
#pragma unroll
    for (int i = 0; i < 4; ++i)
#pragma unroll
      for (int j = 0; j < 4; ++j)
        acc[i][j] = __builtin_amdgcn_mfma_f32_16x16x32_bf16(af[i], bfr[j], acc[i][j], 0, 0, 0);
    __syncthreads();
    cur = nxt;
  }

  if (EPI == 1) {
#pragma unroll
    for (int j = 0; j < 4; ++j) {
      int col = n0 + wc * 64 + j * 16 + (ln & 15);
      float bj = bias[col];
#pragma unroll
      for (int i = 0; i < 4; ++i) {
        int mr = m0 + wr * 64 + i * 16 + ((ln >> 4) << 2);
#pragma unroll
        for (int r = 0; r < 4; ++r)
          outF[(size_t)(mr + r) * N + col] = acc[i][j][r] + bj;
      }
    }
  } else {
    const int s = n0 / 768;  // 0=q 1=k 2=v (block-uniform; 768%128==0)
#pragma unroll
    for (int j = 0; j < 4; ++j) {
      int col = n0 + wc * 64 + j * 16 + (ln & 15);
      float bj = bias[col];
      int ns = col - s * 768;
      int h = ns >> 6, d = ns & 63;
#pragma unroll
      for (int i = 0; i < 4; ++i) {
        int m = m0 + wr * 64 + i * 16 + ((ln >> 4) << 2);
        int b = m >> 11, iseq = m & 2047;
        size_t bh = (size_t)(b * 12 + h);
        if (s == 0) {
#pragma unroll
          for (int r = 0; r < 4; ++r)
            qws[(bh * 2048 + iseq + r) * 64 + d] = f2bf((acc[i][j][r] + bj) * QSCALE);
        } else if (s == 1) {
#pragma unroll
          for (int r = 0; r < 4; ++r)
            kws[(bh * 2048 + iseq + r) * 64 + d] = f2bf(acc[i][j][r] + bj);
        } else {
          // V^T in LDS-READY layout: [bh][tile=k>>5][wc=(k>>3)&3][d][j=k&7].
          // Each 32-kv tile is a contiguous 4KB blob whose linear order is
          // exactly what attn's global_load_lds staging needs (dest linear,
          // source linear, fully coalesced both sides).
          u32x2 pk = {pack2(acc[i][j][0] + bj, acc[i][j][1] + bj),
                      pack2(acc[i][j][2] + bj, acc[i][j][3] + bj)};
          *(u32x2*)(vtws + ((size_t)bh * 64 + (iseq >> 5)) * 2048 +
                    ((iseq >> 3) & 3) * 512 + (size_t)d * 8 + (iseq & 7)) = pk;
        }
      }
    }
  }
}

// ---------------------------------------------------------------- flash attn
// R3 post-mortem: per-lane V global loads are a ~200-900cy dependency inside
// the serial QK->exp->PV chain; at 3 waves/SIMD it cannot be hidden (R2/R3 =
// ~145us vs R0's 65.5 with LDS-staged V). R4 merges the proven-good pieces:
//   - V back in LDS via async global_load_lds, double-buffered (R0 property)
//   - 64q/wave x half-KV dataflow: each K/V fragment read feeds TWO q-groups
//     -> LDS reads per MFMA halved (R1 property)
//   - KVBLK=32: K tile 4KB + V tile 4KB -> total LDS 33KB -> 3 blocks/CU
//     (R1's occupancy loss fixed); same 32-barrier count as R0.
// K tile [32 kv][8 chunks] with chunk^=(kv&7) swizzle, rows pi-permuted
// (swap bits 2<->3) so PV's P-fragment chunk c is regs [c*8..c*8+7] of s[g]
// for both hi halves — pure in-lane pack. V tile stored [wc][d] (LDS-ready
// from GEMM) -> conflict-free 16B reads, linear 4KB staging blob.
// exp2 shift-invariant softmax (no max), denominator on VALU, KV halves
// combined by plain (O,l) addition via one LDS exchange at the epilogue.
// XCD-chunked swizzle: 6 bh per XCD -> 3MB K+V working set < 4MB L2.
#define SWZ(v) (((v) & 32) | (((v) & 31) ^ (ln & 31)))
__global__ __launch_bounds__(256, 3) void attn_fa(
    const u16* __restrict__ qws, const u16* __restrict__ kws,
    const u16* __restrict__ vtws, u16* __restrict__ aows) {
  __shared__ __align__(16) u16 SM[16384];  // K: [p][buf][2048] | V: 8192 + same
  __shared__ float Ls[256];                // denominator exchange
  const int tid = threadIdx.x, ln = tid & 63, wv = tid >> 6;
  const int lq = ln & 31, hi = ln >> 5;
  const int qw = wv & 1;        // which 64-q chunk of the block's 128 q
  const int p  = wv >> 1;       // which KV half

  // XCD-chunked swizzle: flat = y*16+x; xcd = flat&7 owns bh in [6*xcd,6*xcd+6)
  const int flat = blockIdx.y * 16 + blockIdx.x;
  const int xcd = flat & 7, jj = flat >> 3;
  const int bh = xcd * 6 + (jj % 6);
  const int q0 = (jj / 6) * 128 + qw * 64;

  const int kv0 = p * 1024;
  const size_t kbase = (size_t)bh * 2048 * 64;   // Q/K: [bh][n][64]

  // Q^T B-fragments, two q-groups (col=q=lq, k-rows = dc*16 + hi*8 + 0..7)
  bf16x8 qf[2][4];
#pragma unroll
  for (int g = 0; g < 2; ++g) {
    const u16* qp = qws + kbase + (size_t)(q0 + g * 32 + lq) * 64 + hi * 8;
#pragma unroll
    for (int dc = 0; dc < 4; ++dc) qf[g][dc] = *(const bf16x8*)(qp + dc * 16);
  }

  const f32x16 zc = {};
  f32x16 o0[2] = {}, o1[2] = {};           // O^T per q-group: d 0..31 / 32..63
  float lsum[2] = {0.f, 0.f};              // denom partial sums

  // K read offsets (row lq of [32][8 chunks], chunk^=(lq&7)); V read offsets
  // ([wc][d] layout: wc = c*2+hi, d = lq / 32+lq)
  int koff[4], voff[2];
#pragma unroll
  for (int dc = 0; dc < 4; ++dc)
    koff[dc] = lq * 64 + (((dc * 2 + hi) ^ (lq & 7)) * 8);
#pragma unroll
  for (int c = 0; c < 2; ++c)
    voff[c] = (c * 2 + hi) * 512 + lq * 8;

  // staging: pair p stages its K tile (256 slots x 16B) + V tile (256) with
  // 128 threads; wave qw covers slots [qw*128, qw*128+128) of each.
  // K slot s -> (kv = s>>3, ch' = s&7): LDS linear by s; source row
  // pi(kv) (swap bits 2<->3), source chunk ch'^(kv&7).
  // V slot s -> source is the linear 4KB tile blob (LDS-ready layout).
  const int s0i = qw * 128 + ln, s1i = s0i + 64;
  const int kvA = s0i >> 3, kvB = s1i >> 3;
  const int piA = (kvA & ~12) | ((kvA & 4) << 1) | ((kvA & 8) >> 1);
  const int piB = (kvB & ~12) | ((kvB & 4) << 1) | ((kvB & 8) >> 1);
  const u16* kg0 = kws + kbase + (size_t)(kv0 + piA) * 64 + (((s0i & 7) ^ (kvA & 7)) * 8);
  const u16* kg1 = kws + kbase + (size_t)(kv0 + piB) * 64 + (((s1i & 7) ^ (kvB & 7)) * 8);
  const u16* vg  = vtws + ((size_t)bh * 64 + (kv0 >> 5)) * 2048 + s0i * 8;
  u16* Kb = SM + p * 4096;          // + buf*2048
  u16* Vb = SM + 8192 + p * 4096;
  const int sd = qw * 1024;         // wave's slot base (u16) within a buffer

#define STAGE(buf, kb, t) do { \
    GLOAD16(kg0 + (size_t)(kb) * 64, Kb + (buf) * 2048 + sd); \
    GLOAD16(kg1 + (size_t)(kb) * 64, Kb + (buf) * 2048 + sd + 512); \
    GLOAD16(vg + (size_t)(t) * 2048, Vb + (buf) * 2048 + sd); \
    GLOAD16(vg + (size_t)(t) * 2048 + 512, Vb + (buf) * 2048 + sd + 512); \
  } while (0)

  // prologue: stage tile 0 into buffer 0
  STAGE(0, 0, 0);
  __syncthreads();

  int cur = 0;
  for (int it = 0; it < 32; ++it) {
    const int nxt = cur ^ 1;
    if (it + 1 < 32) STAGE(nxt, (it + 1) * 32, it + 1);
    const u16* kbuf = Kb + cur * 2048;
    const u16* vbuf = Vb + cur * 2048;

    // S^T[k][q]: A = K-tile rows (shared LDS load feeds both q-groups)
    f32x16 s[2];
    {
      bf16x8 kf = *(const bf16x8*)(kbuf + koff[0]);
      s[0] = __builtin_amdgcn_mfma_f32_32x32x16_bf16(kf, qf[0][0], zc, 0, 0, 0);
      s[1] = __builtin_amdgcn_mfma_f32_32x32x16_bf16(kf, qf[1][0], zc, 0, 0, 0);
    }
#pragma unroll
    for (int dc = 1; dc < 4; ++dc) {
      bf16x8 kf = *(const bf16x8*)(kbuf + koff[dc]);
      s[0] = __builtin_amdgcn_mfma_f32_32x32x16_bf16(kf, qf[0][dc], s[0], 0, 0, 0);
      s[1] = __builtin_amdgcn_mfma_f32_32x32x16_bf16(kf, qf[1][dc], s[1], 0, 0, 0);
    }

    // P = exp2(S) (shift-invariant softmax); denominator summed on VALU
#pragma unroll
    for (int g = 0; g < 2; ++g) {
      float a = 0.f;
#pragma unroll
      for (int r = 0; r < 16; ++r) {
        float e = __builtin_amdgcn_exp2f(s[g][r]); s[g][r] = e; a += e;
      }
      lsum[g] += a;
    }

    // PV: V fragments feed both q-groups. With pi-permuted K rows, chunk c
    // (k = c*16 + hi*8 + {0..7}) is regs [c*8..c*8+7] of s[g] for BOTH hi
    // halves — pure in-lane pack, no cross-lane exchange.
#pragma unroll
    for (int c = 0; c < 2; ++c) {
      bf16x8 va = *(const bf16x8*)(vbuf + voff[c]);
      bf16x8 vb2 = *(const bf16x8*)(vbuf + voff[c] + 256);
#pragma unroll
      for (int g = 0; g < 2; ++g) {
        const int base = c * 8;
        u32x4 pw = {pack2(s[g][base + 0], s[g][base + 1]),
                    pack2(s[g][base + 2], s[g][base + 3]),
                    pack2(s[g][base + 4], s[g][base + 5]),
                    pack2(s[g][base + 6], s[g][base + 7])};
        bf16x8 pfrag = __builtin_bit_cast(bf16x8, pw);
        o0[g] = __builtin_amdgcn_mfma_f32_32x32x16_bf16(va, pfrag, o0[g], 0, 0, 0);
        o1[g] = __builtin_amdgcn_mfma_f32_32x32x16_bf16(vb2, pfrag, o1[g], 0, 0, 0);
      }
    }
    __syncthreads();
    cur = nxt;
  }
#undef STAGE

  // per-wave denominator: lane holds 16 of 32 k-rows; partner lane ln^32 has
  // the rest (same q = lq). After shfl both lanes hold the half-KV total.
  float lg[2];
#pragma unroll
  for (int g = 0; g < 2; ++g) {
    lg[g] = lsum[g];
    lg[g] += __shfl_xor(lg[g], 32);
  }

  // combine KV halves: waves p=1 export (O,l); waves p=0 add + store.
  // O exchange packed into SM (32KB = 2 qw-groups x 64 lanes x 64 f32) with
  // XOR swizzle: value v -> col (v&32)|((v&31)^(ln&31)) — conflict-free
  // (lanes ln, ln^32 alias 2-way = free). l goes via Ls.
  float* exO = (float*)SM + qw * 4096 + ln * 64;
  if (p == 1) {
#pragma unroll
    for (int r = 0; r < 16; ++r) {
      exO[SWZ(r)]      = o0[0][r];
      exO[SWZ(16 + r)] = o1[0][r];
      exO[SWZ(32 + r)] = o0[1][r];
      exO[SWZ(48 + r)] = o1[1][r];
    }
    Ls[qw * 128 + ln * 2 + 0] = lg[0];
    Ls[qw * 128 + ln * 2 + 1] = lg[1];
  }
  __syncthreads();
  if (p == 0) {
#pragma unroll
    for (int r = 0; r < 16; ++r) {
      o0[0][r] += exO[SWZ(r)];
      o1[0][r] += exO[SWZ(16 + r)];
      o0[1][r] += exO[SWZ(32 + r)];
      o1[1][r] += exO[SWZ(48 + r)];
    }
    lg[0] += Ls[qw * 128 + ln * 2 + 0];
    lg[1] += Ls[qw * 128 + ln * 2 + 1];

    const int b = bh / 12, h = bh % 12;
#pragma unroll
    for (int g = 0; g < 2; ++g) {
      const float rl = 1.0f / lg[g];
      u16* orow = aows + (size_t)(b * 2048 + q0 + g * 32 + lq) * 768 + h * 64;
#pragma unroll
      for (int t = 0; t < 4; ++t) {
        u32x2 pk0 = {pack2(o0[g][4 * t + 0] * rl, o0[g][4 * t + 1] * rl),
                     pack2(o0[g][4 * t + 2] * rl, o0[g][4 * t + 3] * rl)};
        u32x2 pk1 = {pack2(o1[g][4 * t + 0] * rl, o1[g][4 * t + 1] * rl),
                     pack2(o1[g][4 * t + 2] * rl, o1[g][4 * t + 3] * rl)};
        *(u32x2*)(orow + t * 8 + 4 * hi)      = pk0;   // d = 8t+4hi+r
        *(u32x2*)(orow + 32 + t * 8 + 4 * hi) = pk1;   // d = 32+8t+4hi+r
      }
    }
  }
}

// ---------------------------------------------------------------- launch
extern "C" void kernel_launch(void* const* d_in, const int* in_sizes, int n_in,
                              void* d_out, int out_size, void* d_ws, size_t ws_size,
                              hipStream_t stream) {
  const float* x     = (const float*)d_in[0];
  const float* Wqkv  = (const float*)d_in[1];
  const float* bqkv  = (const float*)d_in[2];
  const float* Wproj = (const float*)d_in[3];
  const float* bproj = (const float*)d_in[4];
  float* out = (float*)d_out;

  u16* xb   = (u16*)d_ws;          // 6291456
  u16* wqb  = xb  + 6291456;       // 1769472
  u16* wpb  = wqb + 1769472;       // 589824
  u16* qws  = wpb + 589824;        // 6291456  [bh][n][64], pre-scaled QSCALE
  u16* kws  = qws + 6291456;       // 6291456  [bh][n][64]
  u16* vtws = kws + 6291456;       // 6291456  [bh][32tile][4wc][64d][8] LDS-ready V^T
  u16* aows = vtws + 6291456;      // 6291456  [b*2048+q][768]

  cvt_bf16<<<6291456 / 8 / 256, 256, 0, stream>>>(x, (unsigned*)xb, 6291456 / 8);
  cvt_bf16<<<1769472 / 8 / 256, 256, 0, stream>>>(Wqkv, (unsigned*)wqb, 1769472 / 8);
  cvt_bf16<<<589824 / 8 / 256, 256, 0, stream>>>(Wproj, (unsigned*)wpb, 589824 / 8);

  gemm_tn<0><<<dim3(64, 18), 256, 0, stream>>>(xb, wqb, bqkv, nullptr,
                                               qws, kws, vtws, 8192, 2304, 768);
  attn_fa<<<dim3(16, 48), 256, 0, stream>>>(qws, kws, vtws, aows);
  gemm_tn<1><<<dim3(64, 6), 256, 0, stream>>>(aows, wpb, bproj, out,
                                              nullptr, nullptr, nullptr,
                                              8192, 768, 768);
}